// Round 16
// baseline (509.202 us; speedup 1.0000x reference)
//
#include <hip/hip_runtime.h>
#include <hip/hip_fp16.h>

#define EPSF 1e-5f
#define GRID_BN 1024

typedef unsigned short u16;
typedef __attribute__((ext_vector_type(8))) short bf16x8s;  // 8 bf16 (4 VGPRs)
typedef __attribute__((ext_vector_type(4))) float f32x4;
typedef _Float16 f16x2v __attribute__((ext_vector_type(2)));

static inline int cdiv(int a, int b) { return (a + b - 1) / b; }

// round-nearest-even f32 -> bf16 bits
__device__ inline u16 bf_rne(float v) {
  unsigned u = __float_as_uint(v);
  u += 0x7fffu + ((u >> 16) & 1u);
  return (u16)(u >> 16);
}

__device__ inline float2 cvt_h2(unsigned r) { return __half22float2(*(__half2*)&r); }

// native packed-fp16 helpers (no __h*2 header intrinsics; clang emits v_pk_*)
__device__ inline f16x2v mk2(float x, float y) {
  f16x2v v; v[0] = (_Float16)x; v[1] = (_Float16)y; return v;
}
__device__ inline f16x2v splat2(float x) { return mk2(x, x); }
__device__ inline f16x2v bc2(unsigned r) { return __builtin_bit_cast(f16x2v, r); }

// fp16 pair dot with f32 accumulate (v_dot2_f32_f16); products exact in f32
__device__ inline float fdot2(f16x2v a, f16x2v b, float c) {
#if __has_builtin(__builtin_amdgcn_fdot2)
  return __builtin_amdgcn_fdot2(a, b, c, false);
#else
  return fmaf((float)a[0], (float)b[0], fmaf((float)a[1], (float)b[1], c));
#endif
}

__device__ inline void st_out(float* p, float v) { *p = v; }
__device__ inline void st_out(u16* p, float v) { *p = __half_as_ushort(__float2half(v)); }

// ---------------- column stats (sum, sumsq); X stride == F ----------------
__global__ void col_stats_kernel(const float* __restrict__ X, float* __restrict__ sums,
                                 int N, int F, int rowsPer) {
  int c = threadIdx.x;
  if (c >= F) return;
  int r0 = blockIdx.x * rowsPer;
  int r1 = min(N, r0 + rowsPer);
  float s = 0.f, sq = 0.f;
  for (int r = r0; r < r1; ++r) {
    float v = X[(size_t)r * F + c];
    s += v; sq += v * v;
  }
  atomicAdd(&sums[c], s);
  atomicAdd(&sums[512 + c], sq);
}

// ---------------- BN apply -> fp32 (BN2) ----------------
__global__ void bn_apply_kernel(const float* __restrict__ X, float* __restrict__ Y,
                                const float* __restrict__ sums,
                                const float* __restrict__ g, const float* __restrict__ b,
                                int N, int F, int outW, int rowsPer, int relu) {
  int c = threadIdx.x;
  if (c >= outW) return;
  float sc = 0.f, bb = 0.f;
  if (c < F) {
    float invN = 1.f / (float)N;
    float mu = sums[c] * invN;
    float var = sums[512 + c] * invN - mu * mu;
    sc = g[c] * rsqrtf(var + EPSF);
    bb = b[c] - mu * sc;
  }
  int r0 = blockIdx.x * rowsPer, r1 = min(N, r0 + rowsPer);
  for (int r = r0; r < r1; ++r) {
    float v = (c < F) ? X[(size_t)r * F + c] * sc + bb : 0.f;
    if (relu) v = fmaxf(v, 0.f);
    Y[(size_t)r * outW + c] = v;
  }
}

// ---------------- BN apply -> single bf16 plane (BN0, BN1) ----------------
__global__ void bn_bf16_kernel(const float* __restrict__ X, u16* __restrict__ Y,
                               const float* __restrict__ sums,
                               const float* __restrict__ g, const float* __restrict__ b,
                               int N, int F, int outW, int rowsPer, int relu) {
  int c = threadIdx.x;
  if (c >= outW) return;
  float sc = 0.f, bb = 0.f;
  if (c < F) {
    float invN = 1.f / (float)N;
    float mu = sums[c] * invN;
    float var = sums[512 + c] * invN - mu * mu;
    sc = g[c] * rsqrtf(var + EPSF);
    bb = b[c] - mu * sc;
  }
  int r0 = blockIdx.x * rowsPer, r1 = min(N, r0 + rowsPer);
  for (int r = r0; r < r1; ++r) {
    float v = (c < F) ? X[(size_t)r * F + c] * sc + bb : 0.f;
    if (relu) v = fmaxf(v, 0.f);
    Y[(size_t)r * outW + c] = bf_rne(v);
  }
}

// ---------------- weights: transpose + concat + pad -> [2M][Kp] bf16 ----------------
__global__ void wt_bf16_kernel(const float* __restrict__ Wa, const float* __restrict__ Wb,
                               u16* __restrict__ W, int K, int Kp, int M) {
  int idx = blockIdx.x * blockDim.x + threadIdx.x;
  if (idx >= 2 * M * Kp) return;
  int col = idx / Kp;
  int k = idx - col * Kp;
  float v = 0.f;
  if (k < K) v = (col < M) ? Wa[(size_t)k * M + col] : Wb[(size_t)k * M + (col - M)];
  W[idx] = bf_rne(v);
}

// ---------------- bf16 MFMA GEMM: C(NxMout) = A B^T ----------------
template <typename OutT>
__global__ __launch_bounds__(256) void gemm_mfma(
    const u16* __restrict__ A, const u16* __restrict__ B,
    OutT* __restrict__ C, int N, int Kp, int ldc) {
  __shared__ u16 sA[128 * 40], sB[128 * 40];
  int tid = threadIdx.x;
  int brow = blockIdx.x * 128, bcol = blockIdx.y * 128;
  int stR = tid >> 1;
  int stC0 = (tid & 1) * 2;
  bool aok = (brow + stR) < N;
  const u16* pA = A + (size_t)(brow + stR) * Kp + stC0 * 8;
  const u16* pB = B + (size_t)(bcol + stR) * Kp + stC0 * 8;
  const uint4 Z = make_uint4(0u, 0u, 0u, 0u);
  uint4 ra0 = aok ? *(const uint4*)(pA) : Z;
  uint4 ra1 = aok ? *(const uint4*)(pA + 8) : Z;
  uint4 rb0 = *(const uint4*)(pB);
  uint4 rb1 = *(const uint4*)(pB + 8);
  f32x4 acc[4][4] = {};
  int lane = tid & 63;
  int wv = tid >> 6, wr = wv >> 1, wc = wv & 1;
  int fr = lane & 15, kch = (lane >> 4) * 8;
  int ldsw = stR * 40 + stC0 * 8;
  for (int k0 = 0;;) {
    __syncthreads();
    *(uint4*)&sA[ldsw] = ra0; *(uint4*)&sA[ldsw + 8] = ra1;
    *(uint4*)&sB[ldsw] = rb0; *(uint4*)&sB[ldsw + 8] = rb1;
    __syncthreads();
    int kn = k0 + 32;
    if (kn < Kp) {  // prefetch next k-slab under the MFMA body
      ra0 = aok ? *(const uint4*)(pA + kn) : Z;
      ra1 = aok ? *(const uint4*)(pA + kn + 8) : Z;
      rb0 = *(const uint4*)(pB + kn);
      rb1 = *(const uint4*)(pB + kn + 8);
    }
    bf16x8s af[4], bf[4];
#pragma unroll
    for (int i = 0; i < 4; ++i) {
      af[i] = *(const bf16x8s*)&sA[(wr * 64 + i * 16 + fr) * 40 + kch];
      bf[i] = *(const bf16x8s*)&sB[(wc * 64 + i * 16 + fr) * 40 + kch];
    }
#pragma unroll
    for (int i = 0; i < 4; ++i)
#pragma unroll
      for (int j = 0; j < 4; ++j)
        acc[i][j] = __builtin_amdgcn_mfma_f32_16x16x32_bf16(af[i], bf[j], acc[i][j], 0, 0, 0);
    k0 = kn;
    if (k0 >= Kp) break;
  }
#pragma unroll
  for (int i = 0; i < 4; ++i) {
    int growb = brow + wr * 64 + i * 16 + (lane >> 4) * 4;
#pragma unroll
    for (int j = 0; j < 4; ++j) {
      int gcol = bcol + wc * 64 + j * 16 + fr;
#pragma unroll
      for (int r = 0; r < 4; ++r) {
        int grow = growb + r;
        if (grow < N) st_out(&C[(size_t)grow * ldc + gcol], acc[i][j][r]);
      }
    }
  }
}

// ---------------- CSR build ----------------
__global__ void count_kernel(const int* __restrict__ dst, int* __restrict__ cnt, int E) {
  int e = blockIdx.x * blockDim.x + threadIdx.x;
  if (e < E) atomicAdd(&cnt[dst[e]], 1);
}

__global__ void scan_blk_kernel(const int* __restrict__ cnt, int* __restrict__ row_ptr,
                                int* __restrict__ bsum, int N) {
  __shared__ int lds[1024];
  int tid = threadIdx.x;
  int i = blockIdx.x * 1024 + tid;
  int v = (i < N) ? cnt[i] : 0;
  lds[tid] = v;
  __syncthreads();
  for (int o = 1; o < 1024; o <<= 1) {
    int t = (tid >= o) ? lds[tid - o] : 0;
    __syncthreads();
    lds[tid] += t;
    __syncthreads();
  }
  if (i < N) row_ptr[i] = lds[tid] - v;
  if (tid == 1023) bsum[blockIdx.x] = lds[1023];
}

__global__ void scan_kernel(const int* __restrict__ cnt, int* __restrict__ row_ptr, int N) {
  __shared__ int lds[1024];
  __shared__ int carry;
  int tid = threadIdx.x;
  if (tid == 0) carry = 0;
  __syncthreads();
  for (int base = 0; base < N; base += 1024) {
    int i = base + tid;
    int v = (i < N) ? cnt[i] : 0;
    lds[tid] = v;
    __syncthreads();
    for (int o = 1; o < 1024; o <<= 1) {
      int t = (tid >= o) ? lds[tid - o] : 0;
      __syncthreads();
      lds[tid] += t;
      __syncthreads();
    }
    int incl = lds[tid];
    if (i < N) row_ptr[i] = carry + incl - v;
    __syncthreads();
    if (tid == 1023) carry += incl;
    __syncthreads();
  }
  if (tid == 0) row_ptr[N] = carry;
}

// adds chunk offsets AND writes the fill[] copy
__global__ void scan_add_kernel(int* __restrict__ row_ptr, int* __restrict__ fill,
                                const int* __restrict__ bexc, int N, int nb) {
  int i = blockIdx.x * blockDim.x + threadIdx.x;
  if (i < N) {
    int v = row_ptr[i] + bexc[i >> 10];
    row_ptr[i] = v;
    fill[i] = v;
  }
  if (i == 0) row_ptr[N] = bexc[nb];
}

// edge records in CSR order: {src, half2(ea0,ea1)} -- 8B
__global__ void scatter_rec_kernel(const int* __restrict__ dst, const int* __restrict__ src,
                                   const float* __restrict__ ea, int* __restrict__ fill,
                                   int2* __restrict__ recs, int E) {
  int e = blockIdx.x * blockDim.x + threadIdx.x;
  if (e < E) {
    int p = atomicAdd(&fill[dst[e]], 1);
    unsigned h0 = __half_as_ushort(__float2half(ea[2 * (size_t)e]));
    unsigned h1 = __half_as_ushort(__float2half(ea[2 * (size_t)e + 1]));
    int2 r;
    r.x = src[e];
    r.y = (int)(h0 | (h1 << 16));
    recs[p] = r;
  }
}

// ---------------- GATv2 layer 1: H=2, D=256 (fp16 xlr), one WAVE per node ----------------
// Rotation-free 3-slot modulo schedule (12-edge rounds, MLP~8, zero slot copies)
// + v_fma_mix accumulation (f16 sources feed f32 FMA directly, no cvt).
struct Edge1 { uint2 raw; f16x2v ea; };

__global__ __launch_bounds__(256) void gat1_kernel(
    const u16* __restrict__ xl, const u16* __restrict__ xr, int ldx,
    const int2* __restrict__ recs, const int* __restrict__ row_ptr,
    const float* __restrict__ We, const float* __restrict__ att,
    const float* __restrict__ bias, float* __restrict__ out, int Nn) {
  int n = __builtin_amdgcn_readfirstlane(blockIdx.x * 4 + (threadIdx.x >> 6));
  if (n >= Nn) return;
  int lane = threadIdx.x & 63;
  int c4 = lane * 4;
  const float4 we0f = *(const float4*)(We + c4);
  const float4 we1f = *(const float4*)(We + 256 + c4);
  const float4 atf = *(const float4*)(att + c4);
  const f16x2v we0a = mk2(we0f.x, we0f.y), we0b = mk2(we0f.z, we0f.w);
  const f16x2v we1a = mk2(we1f.x, we1f.y), we1b = mk2(we1f.z, we1f.w);
  const f16x2v atta = mk2(atf.x, atf.y), attb = mk2(atf.z, atf.w);
  const f16x2v k02 = splat2(0.2f);
  uint2 xrr = *(const uint2*)(xr + (size_t)n * ldx + c4);
  const f16x2v xra = bc2(xrr.x), xrb = bc2(xrr.y);
  int start = row_ptr[n];
  int deg = row_ptr[n + 1] - start;
  float4 acc = {0.f, 0.f, 0.f, 0.f};
  float sacc = 0.f;

  auto lde = [&](int i) {
    int2 r = recs[start + i];
    Edge1 t;
    int sv = __builtin_amdgcn_readfirstlane(r.x);
    t.ea = bc2((unsigned)r.y);
    t.raw = *(const uint2*)(xl + (size_t)sv * ldx + c4);
    return t;
  };
  auto zpart = [&](const Edge1& t) {
    f16x2v e0h = __builtin_shufflevector(t.ea, t.ea, 0, 0);
    f16x2v e1h = __builtin_shufflevector(t.ea, t.ea, 1, 1);
    f16x2v ra = bc2(t.raw.x), rb = bc2(t.raw.y);
    f16x2v za = e1h * we1a + (e0h * we0a + (ra + xra));
    f16x2v zb = e1h * we1b + (e0h * we0b + (rb + xrb));
    za = __builtin_elementwise_max(za, za * k02);   // leaky for both signs
    zb = __builtin_elementwise_max(zb, zb * k02);
    return fdot2(zb, attb, fdot2(za, atta, 0.f));
  };
  auto accum = [&](const Edge1& t, float p) {
    f16x2v ra = bc2(t.raw.x), rb = bc2(t.raw.y);
    acc.x = fmaf((float)ra[0], p, acc.x);   // v_fma_mix_f32: f16 src, no cvt
    acc.y = fmaf((float)ra[1], p, acc.y);
    acc.z = fmaf((float)rb[0], p, acc.z);
    acc.w = fmaf((float)rb[1], p, acc.w);
    sacc += p;
  };
  auto consume4 = [&](const Edge1& A, const Edge1& B, const Edge1& C, const Edge1& D) {
    float p0 = zpart(A), p1 = zpart(B), p2 = zpart(C), p3 = zpart(D);
#pragma unroll
    for (int o = 16; o > 0; o >>= 1) {
      p0 += __shfl_xor(p0, o, 32);
      p1 += __shfl_xor(p1, o, 32);
      p2 += __shfl_xor(p2, o, 32);
      p3 += __shfl_xor(p3, o, 32);
    }
    p0 = __expf(p0); p1 = __expf(p1); p2 = __expf(p2); p3 = __expf(p3);
    accum(A, p0); accum(B, p1); accum(C, p2); accum(D, p3);
  };

  int full = deg & ~3;
  // 3 named 4-edge slot sets; roles rotate STATICALLY (no register copies).
  Edge1 a0{}, a1{}, a2{}, a3{}, b0{}, b1{}, b2{}, b3{}, g0{}, g1{}, g2{}, g3{};
  if (full >= 4) { a0 = lde(0); a1 = lde(1); a2 = lde(2); a3 = lde(3); }
  if (full >= 8) { b0 = lde(4); b1 = lde(5); b2 = lde(6); b3 = lde(7); }
  int j = 0;
  while (j + 12 <= full) {
    g0 = lde(j + 8); g1 = lde(j + 9); g2 = lde(j + 10); g3 = lde(j + 11);
    consume4(a0, a1, a2, a3);
    if (j + 16 <= full) { a0 = lde(j + 12); a1 = lde(j + 13); a2 = lde(j + 14); a3 = lde(j + 15); }
    consume4(b0, b1, b2, b3);
    if (j + 20 <= full) { b0 = lde(j + 16); b1 = lde(j + 17); b2 = lde(j + 18); b3 = lde(j + 19); }
    consume4(g0, g1, g2, g3);
    j += 12;
  }
  int rem = full - j;             // 0, 4, or 8
  if (rem >= 4) consume4(a0, a1, a2, a3);
  if (rem == 8) consume4(b0, b1, b2, b3);
  for (int t = full; t < deg; ++t) {
    Edge1 T = lde(t);
    float p = zpart(T);
#pragma unroll
    for (int o = 16; o > 0; o >>= 1) p += __shfl_xor(p, o, 32);
    accum(T, __expf(p));
  }

  float inv = 1.f / ((sacc + 1e-16f) * (float)(deg > 0 ? deg : 1));
  float4 o4;
  o4.x = acc.x * inv + bias[c4];
  o4.y = acc.y * inv + bias[c4 + 1];
  o4.z = acc.z * inv + bias[c4 + 2];
  o4.w = acc.w * inv + bias[c4 + 3];
  *(float4*)(out + (size_t)n * 256 + c4) = o4;
}

// ---------------- GATv2 layer 2: H=1, D=128 (fp16 xlr), one WAVE per node ----------------
struct Edge2 { unsigned raw; f16x2v ea; };

__global__ __launch_bounds__(256) void gat2_kernel(
    const u16* __restrict__ xl, const u16* __restrict__ xr, int ldx,
    const int2* __restrict__ recs, const int* __restrict__ row_ptr,
    const float* __restrict__ We, const float* __restrict__ att,
    const float* __restrict__ bias, float* __restrict__ out, int Nn) {
  int n = __builtin_amdgcn_readfirstlane(blockIdx.x * 4 + (threadIdx.x >> 6));
  if (n >= Nn) return;
  int lane = threadIdx.x & 63;
  int c2 = lane * 2;
  const float2 we0f = *(const float2*)(We + c2);
  const float2 we1f = *(const float2*)(We + 128 + c2);
  const float2 atf = *(const float2*)(att + c2);
  const f16x2v we0a = mk2(we0f.x, we0f.y);
  const f16x2v we1a = mk2(we1f.x, we1f.y);
  const f16x2v atta = mk2(atf.x, atf.y);
  const f16x2v k02 = splat2(0.2f);
  unsigned xrr = *(const unsigned*)(xr + (size_t)n * ldx + c2);
  const f16x2v xra = bc2(xrr);
  int start = row_ptr[n];
  int deg = row_ptr[n + 1] - start;
  float2 acc = {0.f, 0.f};
  float sacc = 0.f;

  auto lde = [&](int i) {
    int2 r = recs[start + i];
    Edge2 t;
    int sv = __builtin_amdgcn_readfirstlane(r.x);
    t.ea = bc2((unsigned)r.y);
    t.raw = *(const unsigned*)(xl + (size_t)sv * ldx + c2);
    return t;
  };
  auto zpart = [&](const Edge2& t) {
    f16x2v e0h = __builtin_shufflevector(t.ea, t.ea, 0, 0);
    f16x2v e1h = __builtin_shufflevector(t.ea, t.ea, 1, 1);
    f16x2v ra = bc2(t.raw);
    f16x2v za = e1h * we1a + (e0h * we0a + (ra + xra));
    za = __builtin_elementwise_max(za, za * k02);
    return fdot2(za, atta, 0.f);
  };
  auto accum = [&](const Edge2& t, float p) {
    f16x2v ra = bc2(t.raw);
    acc.x = fmaf((float)ra[0], p, acc.x);
    acc.y = fmaf((float)ra[1], p, acc.y);
    sacc += p;
  };
  auto consume4 = [&](const Edge2& A, const Edge2& B, const Edge2& C, const Edge2& D) {
    float p0 = zpart(A), p1 = zpart(B), p2 = zpart(C), p3 = zpart(D);
#pragma unroll
    for (int o = 32; o > 0; o >>= 1) {
      p0 += __shfl_xor(p0, o);
      p1 += __shfl_xor(p1, o);
      p2 += __shfl_xor(p2, o);
      p3 += __shfl_xor(p3, o);
    }
    p0 = __expf(p0); p1 = __expf(p1); p2 = __expf(p2); p3 = __expf(p3);
    accum(A, p0); accum(B, p1); accum(C, p2); accum(D, p3);
  };

  int full = deg & ~3;
  Edge2 a0{}, a1{}, a2{}, a3{}, b0{}, b1{}, b2{}, b3{}, g0{}, g1{}, g2{}, g3{};
  if (full >= 4) { a0 = lde(0); a1 = lde(1); a2 = lde(2); a3 = lde(3); }
  if (full >= 8) { b0 = lde(4); b1 = lde(5); b2 = lde(6); b3 = lde(7); }
  int j = 0;
  while (j + 12 <= full) {
    g0 = lde(j + 8); g1 = lde(j + 9); g2 = lde(j + 10); g3 = lde(j + 11);
    consume4(a0, a1, a2, a3);
    if (j + 16 <= full) { a0 = lde(j + 12); a1 = lde(j + 13); a2 = lde(j + 14); a3 = lde(j + 15); }
    consume4(b0, b1, b2, b3);
    if (j + 20 <= full) { b0 = lde(j + 16); b1 = lde(j + 17); b2 = lde(j + 18); b3 = lde(j + 19); }
    consume4(g0, g1, g2, g3);
    j += 12;
  }
  int rem = full - j;
  if (rem >= 4) consume4(a0, a1, a2, a3);
  if (rem == 8) consume4(b0, b1, b2, b3);
  for (int t = full; t < deg; ++t) {
    Edge2 T = lde(t);
    float p = zpart(T);
#pragma unroll
    for (int o = 32; o > 0; o >>= 1) p += __shfl_xor(p, o);
    accum(T, __expf(p));
  }

  float inv = 1.f / ((sacc + 1e-16f) * (float)(deg > 0 ? deg : 1));
  float2 o2;
  o2.x = acc.x * inv + bias[c2];
  o2.y = acc.y * inv + bias[c2 + 1];
  *(float2*)(out + (size_t)n * 128 + c2) = o2;
}

// ---------------- layer-3 (ch=1): one wave per node, edge-parallel lanes ----------------
__global__ void gat3_kernel(const float* __restrict__ xl, const float* __restrict__ xr,
                            const int2* __restrict__ recs, const int* __restrict__ row_ptr,
                            const float* __restrict__ We, const float* __restrict__ att,
                            const float* __restrict__ bias, float* __restrict__ out, int Nn) {
  int n = blockIdx.x * 4 + (threadIdx.x >> 6);
  int lane = threadIdx.x & 63;
  if (n >= Nn) return;
  float we0 = We[0], we1 = We[1], a = att[0];
  float xr_n = xr[n];
  int s0 = row_ptr[n], s1 = row_ptr[n + 1];
  float accp = 0.f, accs = 0.f;
  for (int i = s0 + lane; i < s1; i += 64) {
    int2 r = recs[i];
    f16x2v ea = bc2((unsigned)r.y);
    float xls = xl[r.x];
    float z = xls + xr_n + (float)ea[0] * we0 + (float)ea[1] * we1;
    z = (z > 0.f) ? z : 0.2f * z;
    float p = __expf(z * a);
    accp += p * xls;
    accs += p;
  }
#pragma unroll
  for (int o = 32; o > 0; o >>= 1) {
    accp += __shfl_xor(accp, o);
    accs += __shfl_xor(accs, o);
  }
  int deg = s1 - s0;
  if (lane == 0) out[n] = accp / ((accs + 1e-16f) * (float)(deg > 0 ? deg : 1)) + bias[0];
}

// ---------------- dual row dot: o1[n]=A[n,:].w1, o2[n]=A[n,:].w2 (one A pass) ----------------
__global__ void rowdot2_kernel(const float* __restrict__ A,
                               const float* __restrict__ w1, const float* __restrict__ w2,
                               float* __restrict__ o1, float* __restrict__ o2, int Nn, int K) {
  int n = blockIdx.x * 4 + (threadIdx.x >> 6);
  int lane = threadIdx.x & 63;
  if (n >= Nn) return;
  float p = 0.f, q = 0.f;
  for (int k = lane; k < K; k += 64) {
    float a = A[(size_t)n * K + k];
    p += a * w1[k];
    q += a * w2[k];
  }
#pragma unroll
  for (int o = 32; o > 0; o >>= 1) {
    p += __shfl_xor(p, o);
    q += __shfl_xor(q, o);
  }
  if (lane == 0) { o1[n] = p; o2[n] = q; }
}

extern "C" void kernel_launch(void* const* d_in, const int* in_sizes, int n_in,
                              void* d_out, int out_size, void* d_ws, size_t ws_size,
                              hipStream_t stream) {
  const float* x     = (const float*)d_in[0];
  const int*   ei    = (const int*)d_in[1];
  const float* ea    = (const float*)d_in[2];
  const float* bn0_g = (const float*)d_in[3];
  const float* bn0_b = (const float*)d_in[4];
  const float* Wl1   = (const float*)d_in[5];
  const float* Wr1   = (const float*)d_in[6];
  const float* We1   = (const float*)d_in[7];
  const float* att1  = (const float*)d_in[8];
  const float* b1    = (const float*)d_in[9];
  const float* bn1_g = (const float*)d_in[10];
  const float* bn1_b = (const float*)d_in[11];
  const float* Wl2   = (const float*)d_in[12];
  const float* Wr2   = (const float*)d_in[13];
  const float* We2   = (const float*)d_in[14];
  const float* att2  = (const float*)d_in[15];
  const float* b2    = (const float*)d_in[16];
  const float* bn2_g = (const float*)d_in[17];
  const float* bn2_b = (const float*)d_in[18];
  const float* Wl3   = (const float*)d_in[19];
  const float* Wr3   = (const float*)d_in[20];
  const float* We3   = (const float*)d_in[21];
  const float* att3  = (const float*)d_in[22];
  const float* b3    = (const float*)d_in[23];

  const int F = 301;
  const int Kp1 = 320;
  const int N = in_sizes[0] / F;
  const int E = in_sizes[1] / 2;
  const int* srcv = ei;
  const int* dstv = ei + E;

  // ---- workspace layout, regions time-shared ----
  float* fws = (float*)d_ws;
  float* RA = fws;                              // N*320 f
  float* RB = RA + (size_t)N * 320;             // N*384 f
  float* stats = RB + (size_t)N * 384;          // 1024
  u16* wt1 = (u16*)(stats + 1024);              // 512*320 bf16
  u16* wt2 = wt1 + (size_t)512 * 320;           // 256*256 bf16
  float* xl3 = (float*)(wt2 + (size_t)256 * 256);
  float* xr3 = xl3 + N;
  char* pi = (char*)(xr3 + N);
  pi += (16 - ((size_t)pi & 15)) & 15;          // 16B-align records
  int2* recs = (int2*)pi;                       // E records (8B each)
  int* row_ptr = (int*)(recs + E);              // N+1
  int* fill    = row_ptr + (N + 1);             // N
  int* bsum    = fill + N;                      // nb (<=64)
  int* bexc    = bsum + 64;                     // nb+1

  // region aliases along the timeline
  u16* Abf = (u16*)RA;                          // N x 320 bf16
  u16* xlr1 = (u16*)RB;                         // N x 512 fp16 (xl1 | xr1)
  float* g1out = RA;                            // N x 256 f (gat1 out)
  u16* h1bf = (u16*)RB;                         // N x 256 bf16
  u16* xlr2 = h1bf + (size_t)N * 256;           // N x 256 fp16 (xl2 | xr2)
  float* g2out = RA;                            // N x 128 f
  float* h2 = RA + (size_t)N * 128;             // N x 128 f

  // ---- CSR by dst (parallel 3-phase scan), edge records ----
  int nb = cdiv(N, 1024);
  hipMemsetAsync(fill, 0, (size_t)N * sizeof(int), stream);
  count_kernel<<<cdiv(E, 256), 256, 0, stream>>>(dstv, fill, E);
  scan_blk_kernel<<<nb, 1024, 0, stream>>>(fill, row_ptr, bsum, N);
  scan_kernel<<<1, 1024, 0, stream>>>(bsum, bexc, nb);
  scan_add_kernel<<<cdiv(N, 256), 256, 0, stream>>>(row_ptr, fill, bexc, N, nb);
  scatter_rec_kernel<<<cdiv(E, 256), 256, 0, stream>>>(dstv, srcv, ea, fill, recs, E);

  // ---- weight prep (single bf16 plane) ----
  wt_bf16_kernel<<<cdiv(512 * Kp1, 256), 256, 0, stream>>>(Wl1, Wr1, wt1, F, Kp1, 256);
  wt_bf16_kernel<<<cdiv(256 * 256, 256), 256, 0, stream>>>(Wl2, Wr2, wt2, 256, 256, 128);

  int rows = cdiv(N, GRID_BN);  // high-occupancy BN grids

  // ---- BN0 -> bf16 A plane ----
  hipMemsetAsync(stats, 0, 1024 * sizeof(float), stream);
  col_stats_kernel<<<GRID_BN, 320, 0, stream>>>(x, stats, N, F, rows);
  bn_bf16_kernel<<<GRID_BN, 320, 0, stream>>>(x, Abf, stats, bn0_g, bn0_b, N, F, Kp1, rows, 0);

  // ---- layer 1: fused [xl|xr] bf16 MFMA GEMM (fp16 out) + edge pass ----
  gemm_mfma<u16><<<dim3(cdiv(N, 128), 4), 256, 0, stream>>>(Abf, wt1, xlr1, N, Kp1, 512);
  gat1_kernel<<<cdiv(N, 4), 256, 0, stream>>>(xlr1, xlr1 + 256, 512, recs, row_ptr,
                                              We1, att1, b1, g1out, N);
  // ---- BN1 + relu -> bf16 h1 plane ----
  hipMemsetAsync(stats, 0, 1024 * sizeof(float), stream);
  col_stats_kernel<<<GRID_BN, 256, 0, stream>>>(g1out, stats, N, 256, rows);
  bn_bf16_kernel<<<GRID_BN, 256, 0, stream>>>(g1out, h1bf, stats, bn1_g, bn1_b, N, 256, 256, rows, 1);

  // ---- layer 2: fused [xl|xr] bf16 MFMA GEMM (fp16 out) + edge pass ----
  gemm_mfma<u16><<<dim3(cdiv(N, 128), 2), 256, 0, stream>>>(h1bf, wt2, xlr2, N, 256, 256);
  gat2_kernel<<<cdiv(N, 4), 256, 0, stream>>>(xlr2, xlr2 + 128, 256, recs, row_ptr,
                                              We2, att2, b2, g2out, N);
  // ---- BN2 + relu -> fp32 h2 ----
  hipMemsetAsync(stats, 0, 1024 * sizeof(float), stream);
  col_stats_kernel<<<GRID_BN, 128, 0, stream>>>(g2out, stats, N, 128, rows);
  bn_apply_kernel<<<GRID_BN, 128, 0, stream>>>(g2out, h2, stats, bn2_g, bn2_b, N, 128, 128, rows, 1);

  // ---- layer 3 (ch=1) ----
  rowdot2_kernel<<<cdiv(N, 4), 256, 0, stream>>>(h2, Wl3, Wr3, xl3, xr3, N, 128);
  gat3_kernel<<<cdiv(N, 4), 256, 0, stream>>>(xl3, xr3, recs, row_ptr,
                                              We3, att3, b3, (float*)d_out, N);
}

// Round 17
// 501.213 us; speedup vs baseline: 1.0159x; 1.0159x over previous
//
#include <hip/hip_runtime.h>
#include <hip/hip_fp16.h>

#define EPSF 1e-5f
#define GRID_BN 1024

typedef unsigned short u16;
typedef __attribute__((ext_vector_type(8))) short bf16x8s;  // 8 bf16 (4 VGPRs)
typedef __attribute__((ext_vector_type(4))) float f32x4;
typedef _Float16 f16x2v __attribute__((ext_vector_type(2)));

static inline int cdiv(int a, int b) { return (a + b - 1) / b; }

// round-nearest-even f32 -> bf16 bits
__device__ inline u16 bf_rne(float v) {
  unsigned u = __float_as_uint(v);
  u += 0x7fffu + ((u >> 16) & 1u);
  return (u16)(u >> 16);
}

__device__ inline float4 cvt_h4(uint2 r) {
  float2 a = __half22float2(*(__half2*)&r.x);
  float2 b = __half22float2(*(__half2*)&r.y);
  return make_float4(a.x, a.y, b.x, b.y);
}
__device__ inline float2 cvt_h2(unsigned r) { return __half22float2(*(__half2*)&r); }

// native packed-fp16 helpers (no __h*2 header intrinsics; clang emits v_pk_*)
__device__ inline f16x2v mk2(float x, float y) {
  f16x2v v; v[0] = (_Float16)x; v[1] = (_Float16)y; return v;
}
__device__ inline f16x2v splat2(float x) { return mk2(x, x); }
__device__ inline f16x2v bc2(unsigned r) { return __builtin_bit_cast(f16x2v, r); }

// fp16 pair dot with f32 accumulate (v_dot2_f32_f16); products exact in f32
__device__ inline float fdot2(f16x2v a, f16x2v b, float c) {
#if __has_builtin(__builtin_amdgcn_fdot2)
  return __builtin_amdgcn_fdot2(a, b, c, false);
#else
  return fmaf((float)a[0], (float)b[0], fmaf((float)a[1], (float)b[1], c));
#endif
}

__device__ inline void st_out(float* p, float v) { *p = v; }
__device__ inline void st_out(u16* p, float v) { *p = __half_as_ushort(__float2half(v)); }

// ---------------- column stats (sum, sumsq); X stride == F ----------------
__global__ void col_stats_kernel(const float* __restrict__ X, float* __restrict__ sums,
                                 int N, int F, int rowsPer) {
  int c = threadIdx.x;
  if (c >= F) return;
  int r0 = blockIdx.x * rowsPer;
  int r1 = min(N, r0 + rowsPer);
  float s = 0.f, sq = 0.f;
  for (int r = r0; r < r1; ++r) {
    float v = X[(size_t)r * F + c];
    s += v; sq += v * v;
  }
  atomicAdd(&sums[c], s);
  atomicAdd(&sums[512 + c], sq);
}

// ---------------- BN apply -> fp32 (BN2) ----------------
__global__ void bn_apply_kernel(const float* __restrict__ X, float* __restrict__ Y,
                                const float* __restrict__ sums,
                                const float* __restrict__ g, const float* __restrict__ b,
                                int N, int F, int outW, int rowsPer, int relu) {
  int c = threadIdx.x;
  if (c >= outW) return;
  float sc = 0.f, bb = 0.f;
  if (c < F) {
    float invN = 1.f / (float)N;
    float mu = sums[c] * invN;
    float var = sums[512 + c] * invN - mu * mu;
    sc = g[c] * rsqrtf(var + EPSF);
    bb = b[c] - mu * sc;
  }
  int r0 = blockIdx.x * rowsPer, r1 = min(N, r0 + rowsPer);
  for (int r = r0; r < r1; ++r) {
    float v = (c < F) ? X[(size_t)r * F + c] * sc + bb : 0.f;
    if (relu) v = fmaxf(v, 0.f);
    Y[(size_t)r * outW + c] = v;
  }
}

// ---------------- BN apply -> single bf16 plane (BN0, BN1) ----------------
__global__ void bn_bf16_kernel(const float* __restrict__ X, u16* __restrict__ Y,
                               const float* __restrict__ sums,
                               const float* __restrict__ g, const float* __restrict__ b,
                               int N, int F, int outW, int rowsPer, int relu) {
  int c = threadIdx.x;
  if (c >= outW) return;
  float sc = 0.f, bb = 0.f;
  if (c < F) {
    float invN = 1.f / (float)N;
    float mu = sums[c] * invN;
    float var = sums[512 + c] * invN - mu * mu;
    sc = g[c] * rsqrtf(var + EPSF);
    bb = b[c] - mu * sc;
  }
  int r0 = blockIdx.x * rowsPer, r1 = min(N, r0 + rowsPer);
  for (int r = r0; r < r1; ++r) {
    float v = (c < F) ? X[(size_t)r * F + c] * sc + bb : 0.f;
    if (relu) v = fmaxf(v, 0.f);
    Y[(size_t)r * outW + c] = bf_rne(v);
  }
}

// ---------------- weights: transpose + concat + pad -> [2M][Kp] bf16 ----------------
__global__ void wt_bf16_kernel(const float* __restrict__ Wa, const float* __restrict__ Wb,
                               u16* __restrict__ W, int K, int Kp, int M) {
  int idx = blockIdx.x * blockDim.x + threadIdx.x;
  if (idx >= 2 * M * Kp) return;
  int col = idx / Kp;
  int k = idx - col * Kp;
  float v = 0.f;
  if (k < K) v = (col < M) ? Wa[(size_t)k * M + col] : Wb[(size_t)k * M + (col - M)];
  W[idx] = bf_rne(v);
}

// ---------------- bf16 MFMA GEMM: C(NxMout) = A B^T ----------------
template <typename OutT>
__global__ __launch_bounds__(256) void gemm_mfma(
    const u16* __restrict__ A, const u16* __restrict__ B,
    OutT* __restrict__ C, int N, int Kp, int ldc) {
  __shared__ u16 sA[128 * 40], sB[128 * 40];
  int tid = threadIdx.x;
  int brow = blockIdx.x * 128, bcol = blockIdx.y * 128;
  int stR = tid >> 1;
  int stC0 = (tid & 1) * 2;
  bool aok = (brow + stR) < N;
  const u16* pA = A + (size_t)(brow + stR) * Kp + stC0 * 8;
  const u16* pB = B + (size_t)(bcol + stR) * Kp + stC0 * 8;
  const uint4 Z = make_uint4(0u, 0u, 0u, 0u);
  uint4 ra0 = aok ? *(const uint4*)(pA) : Z;
  uint4 ra1 = aok ? *(const uint4*)(pA + 8) : Z;
  uint4 rb0 = *(const uint4*)(pB);
  uint4 rb1 = *(const uint4*)(pB + 8);
  f32x4 acc[4][4] = {};
  int lane = tid & 63;
  int wv = tid >> 6, wr = wv >> 1, wc = wv & 1;
  int fr = lane & 15, kch = (lane >> 4) * 8;
  int ldsw = stR * 40 + stC0 * 8;
  for (int k0 = 0;;) {
    __syncthreads();
    *(uint4*)&sA[ldsw] = ra0; *(uint4*)&sA[ldsw + 8] = ra1;
    *(uint4*)&sB[ldsw] = rb0; *(uint4*)&sB[ldsw + 8] = rb1;
    __syncthreads();
    int kn = k0 + 32;
    if (kn < Kp) {  // prefetch next k-slab under the MFMA body
      ra0 = aok ? *(const uint4*)(pA + kn) : Z;
      ra1 = aok ? *(const uint4*)(pA + kn + 8) : Z;
      rb0 = *(const uint4*)(pB + kn);
      rb1 = *(const uint4*)(pB + kn + 8);
    }
    bf16x8s af[4], bf[4];
#pragma unroll
    for (int i = 0; i < 4; ++i) {
      af[i] = *(const bf16x8s*)&sA[(wr * 64 + i * 16 + fr) * 40 + kch];
      bf[i] = *(const bf16x8s*)&sB[(wc * 64 + i * 16 + fr) * 40 + kch];
    }
#pragma unroll
    for (int i = 0; i < 4; ++i)
#pragma unroll
      for (int j = 0; j < 4; ++j)
        acc[i][j] = __builtin_amdgcn_mfma_f32_16x16x32_bf16(af[i], bf[j], acc[i][j], 0, 0, 0);
    k0 = kn;
    if (k0 >= Kp) break;
  }
#pragma unroll
  for (int i = 0; i < 4; ++i) {
    int growb = brow + wr * 64 + i * 16 + (lane >> 4) * 4;
#pragma unroll
    for (int j = 0; j < 4; ++j) {
      int gcol = bcol + wc * 64 + j * 16 + fr;
#pragma unroll
      for (int r = 0; r < 4; ++r) {
        int grow = growb + r;
        if (grow < N) st_out(&C[(size_t)grow * ldc + gcol], acc[i][j][r]);
      }
    }
  }
}

// ---------------- CSR build ----------------
__global__ void count_kernel(const int* __restrict__ dst, int* __restrict__ cnt, int E) {
  int e = blockIdx.x * blockDim.x + threadIdx.x;
  if (e < E) atomicAdd(&cnt[dst[e]], 1);
}

__global__ void scan_blk_kernel(const int* __restrict__ cnt, int* __restrict__ row_ptr,
                                int* __restrict__ bsum, int N) {
  __shared__ int lds[1024];
  int tid = threadIdx.x;
  int i = blockIdx.x * 1024 + tid;
  int v = (i < N) ? cnt[i] : 0;
  lds[tid] = v;
  __syncthreads();
  for (int o = 1; o < 1024; o <<= 1) {
    int t = (tid >= o) ? lds[tid - o] : 0;
    __syncthreads();
    lds[tid] += t;
    __syncthreads();
  }
  if (i < N) row_ptr[i] = lds[tid] - v;
  if (tid == 1023) bsum[blockIdx.x] = lds[1023];
}

__global__ void scan_kernel(const int* __restrict__ cnt, int* __restrict__ row_ptr, int N) {
  __shared__ int lds[1024];
  __shared__ int carry;
  int tid = threadIdx.x;
  if (tid == 0) carry = 0;
  __syncthreads();
  for (int base = 0; base < N; base += 1024) {
    int i = base + tid;
    int v = (i < N) ? cnt[i] : 0;
    lds[tid] = v;
    __syncthreads();
    for (int o = 1; o < 1024; o <<= 1) {
      int t = (tid >= o) ? lds[tid - o] : 0;
      __syncthreads();
      lds[tid] += t;
      __syncthreads();
    }
    int incl = lds[tid];
    if (i < N) row_ptr[i] = carry + incl - v;
    __syncthreads();
    if (tid == 1023) carry += incl;
    __syncthreads();
  }
  if (tid == 0) row_ptr[N] = carry;
}

// adds chunk offsets AND writes the fill[] copy
__global__ void scan_add_kernel(int* __restrict__ row_ptr, int* __restrict__ fill,
                                const int* __restrict__ bexc, int N, int nb) {
  int i = blockIdx.x * blockDim.x + threadIdx.x;
  if (i < N) {
    int v = row_ptr[i] + bexc[i >> 10];
    row_ptr[i] = v;
    fill[i] = v;
  }
  if (i == 0) row_ptr[N] = bexc[nb];
}

// edge records in CSR order: {src, half2(ea0,ea1)} -- 8B
__global__ void scatter_rec_kernel(const int* __restrict__ dst, const int* __restrict__ src,
                                   const float* __restrict__ ea, int* __restrict__ fill,
                                   int2* __restrict__ recs, int E) {
  int e = blockIdx.x * blockDim.x + threadIdx.x;
  if (e < E) {
    int p = atomicAdd(&fill[dst[e]], 1);
    unsigned h0 = __half_as_ushort(__float2half(ea[2 * (size_t)e]));
    unsigned h1 = __half_as_ushort(__float2half(ea[2 * (size_t)e + 1]));
    int2 r;
    r.x = src[e];
    r.y = (int)(h0 | (h1 << 16));
    recs[p] = r;
  }
}

// ---------------- GATv2 layer 1: H=2, D=256 (fp16 xlr), one WAVE per node ----------------
// Triple-buffered 4-edge batches (MLP=8): consume batch j while j+4 arrives and
// j+8 issues. 8B edge records (src + half2 ea) -- no per-edge f32->f16 cvt.
struct Edge1 { uint2 raw; f16x2v ea; };

__global__ __launch_bounds__(256) void gat1_kernel(
    const u16* __restrict__ xl, const u16* __restrict__ xr, int ldx,
    const int2* __restrict__ recs, const int* __restrict__ row_ptr,
    const float* __restrict__ We, const float* __restrict__ att,
    const float* __restrict__ bias, float* __restrict__ out, int Nn) {
  int n = __builtin_amdgcn_readfirstlane(blockIdx.x * 4 + (threadIdx.x >> 6));
  if (n >= Nn) return;
  int lane = threadIdx.x & 63;
  int c4 = lane * 4;
  const float4 we0f = *(const float4*)(We + c4);
  const float4 we1f = *(const float4*)(We + 256 + c4);
  const float4 atf = *(const float4*)(att + c4);
  const f16x2v we0a = mk2(we0f.x, we0f.y), we0b = mk2(we0f.z, we0f.w);
  const f16x2v we1a = mk2(we1f.x, we1f.y), we1b = mk2(we1f.z, we1f.w);
  const f16x2v atta = mk2(atf.x, atf.y), attb = mk2(atf.z, atf.w);
  const f16x2v k02 = splat2(0.2f);
  uint2 xrr = *(const uint2*)(xr + (size_t)n * ldx + c4);
  const f16x2v xra = bc2(xrr.x), xrb = bc2(xrr.y);
  int start = row_ptr[n];
  int deg = row_ptr[n + 1] - start;
  float4 acc = {0.f, 0.f, 0.f, 0.f};
  float sacc = 0.f;

  auto lde = [&](int i) {
    int2 r = recs[start + i];
    Edge1 t;
    int sv = __builtin_amdgcn_readfirstlane(r.x);
    t.ea = bc2((unsigned)r.y);
    t.raw = *(const uint2*)(xl + (size_t)sv * ldx + c4);
    return t;
  };
  auto zpart = [&](const Edge1& t) {
    f16x2v e0h = __builtin_shufflevector(t.ea, t.ea, 0, 0);
    f16x2v e1h = __builtin_shufflevector(t.ea, t.ea, 1, 1);
    f16x2v ra = bc2(t.raw.x), rb = bc2(t.raw.y);
    f16x2v za = e1h * we1a + (e0h * we0a + (ra + xra));
    f16x2v zb = e1h * we1b + (e0h * we0b + (rb + xrb));
    za = __builtin_elementwise_max(za, za * k02);   // leaky for both signs
    zb = __builtin_elementwise_max(zb, zb * k02);
    return fdot2(zb, attb, fdot2(za, atta, 0.f));
  };
  auto accum = [&](const Edge1& t, float p) {
    float4 xc = cvt_h4(t.raw);
    acc.x += p * xc.x;
    acc.y += p * xc.y;
    acc.z += p * xc.z;
    acc.w += p * xc.w;
    sacc += p;
  };
  auto consume4 = [&](const Edge1& A, const Edge1& B, const Edge1& C, const Edge1& D) {
    float p0 = zpart(A), p1 = zpart(B), p2 = zpart(C), p3 = zpart(D);
#pragma unroll
    for (int o = 16; o > 0; o >>= 1) {
      p0 += __shfl_xor(p0, o, 32);
      p1 += __shfl_xor(p1, o, 32);
      p2 += __shfl_xor(p2, o, 32);
      p3 += __shfl_xor(p3, o, 32);
    }
    p0 = __expf(p0); p1 = __expf(p1); p2 = __expf(p2); p3 = __expf(p3);
    accum(A, p0); accum(B, p1); accum(C, p2); accum(D, p3);
  };

  int full = deg & ~3;
  Edge1 c0{}, c1{}, c2{}, c3{}, m0{}, m1{}, m2{}, m3{};
  if (full >= 4) { c0 = lde(0); c1 = lde(1); c2 = lde(2); c3 = lde(3); }
  if (full >= 8) { m0 = lde(4); m1 = lde(5); m2 = lde(6); m3 = lde(7); }
  int j = 0;
  while (j + 8 <= full) {
    Edge1 t0{}, t1{}, t2{}, t3{};
    if (j + 12 <= full) { t0 = lde(j + 8); t1 = lde(j + 9); t2 = lde(j + 10); t3 = lde(j + 11); }
    consume4(c0, c1, c2, c3);
    c0 = m0; c1 = m1; c2 = m2; c3 = m3;
    m0 = t0; m1 = t1; m2 = t2; m3 = t3;
    j += 4;
  }
  if (full >= 4) consume4(c0, c1, c2, c3);
  for (int t = full; t < deg; ++t) {
    Edge1 T = lde(t);
    float p = zpart(T);
#pragma unroll
    for (int o = 16; o > 0; o >>= 1) p += __shfl_xor(p, o, 32);
    accum(T, __expf(p));
  }

  float inv = 1.f / ((sacc + 1e-16f) * (float)(deg > 0 ? deg : 1));
  float4 o4;
  o4.x = acc.x * inv + bias[c4];
  o4.y = acc.y * inv + bias[c4 + 1];
  o4.z = acc.z * inv + bias[c4 + 2];
  o4.w = acc.w * inv + bias[c4 + 3];
  *(float4*)(out + (size_t)n * 256 + c4) = o4;
}

// ---------------- GATv2 layer 2: H=1, D=128 (fp16 xlr), one WAVE per node ----------------
struct Edge2 { unsigned raw; f16x2v ea; };

__global__ __launch_bounds__(256) void gat2_kernel(
    const u16* __restrict__ xl, const u16* __restrict__ xr, int ldx,
    const int2* __restrict__ recs, const int* __restrict__ row_ptr,
    const float* __restrict__ We, const float* __restrict__ att,
    const float* __restrict__ bias, float* __restrict__ out, int Nn) {
  int n = __builtin_amdgcn_readfirstlane(blockIdx.x * 4 + (threadIdx.x >> 6));
  if (n >= Nn) return;
  int lane = threadIdx.x & 63;
  int c2 = lane * 2;
  const float2 we0f = *(const float2*)(We + c2);
  const float2 we1f = *(const float2*)(We + 128 + c2);
  const float2 atf = *(const float2*)(att + c2);
  const f16x2v we0a = mk2(we0f.x, we0f.y);
  const f16x2v we1a = mk2(we1f.x, we1f.y);
  const f16x2v atta = mk2(atf.x, atf.y);
  const f16x2v k02 = splat2(0.2f);
  unsigned xrr = *(const unsigned*)(xr + (size_t)n * ldx + c2);
  const f16x2v xra = bc2(xrr);
  int start = row_ptr[n];
  int deg = row_ptr[n + 1] - start;
  float2 acc = {0.f, 0.f};
  float sacc = 0.f;

  auto lde = [&](int i) {
    int2 r = recs[start + i];
    Edge2 t;
    int sv = __builtin_amdgcn_readfirstlane(r.x);
    t.ea = bc2((unsigned)r.y);
    t.raw = *(const unsigned*)(xl + (size_t)sv * ldx + c2);
    return t;
  };
  auto zpart = [&](const Edge2& t) {
    f16x2v e0h = __builtin_shufflevector(t.ea, t.ea, 0, 0);
    f16x2v e1h = __builtin_shufflevector(t.ea, t.ea, 1, 1);
    f16x2v ra = bc2(t.raw);
    f16x2v za = e1h * we1a + (e0h * we0a + (ra + xra));
    za = __builtin_elementwise_max(za, za * k02);
    return fdot2(za, atta, 0.f);
  };
  auto accum = [&](const Edge2& t, float p) {
    float2 xc = cvt_h2(t.raw);
    acc.x += p * xc.x;
    acc.y += p * xc.y;
    sacc += p;
  };
  auto consume4 = [&](const Edge2& A, const Edge2& B, const Edge2& C, const Edge2& D) {
    float p0 = zpart(A), p1 = zpart(B), p2 = zpart(C), p3 = zpart(D);
#pragma unroll
    for (int o = 32; o > 0; o >>= 1) {
      p0 += __shfl_xor(p0, o);
      p1 += __shfl_xor(p1, o);
      p2 += __shfl_xor(p2, o);
      p3 += __shfl_xor(p3, o);
    }
    p0 = __expf(p0); p1 = __expf(p1); p2 = __expf(p2); p3 = __expf(p3);
    accum(A, p0); accum(B, p1); accum(C, p2); accum(D, p3);
  };

  int full = deg & ~3;
  Edge2 c0{}, c1{}, c2v{}, c3{}, m0{}, m1{}, m2{}, m3{};
  if (full >= 4) { c0 = lde(0); c1 = lde(1); c2v = lde(2); c3 = lde(3); }
  if (full >= 8) { m0 = lde(4); m1 = lde(5); m2 = lde(6); m3 = lde(7); }
  int j = 0;
  while (j + 8 <= full) {
    Edge2 t0{}, t1{}, t2{}, t3{};
    if (j + 12 <= full) { t0 = lde(j + 8); t1 = lde(j + 9); t2 = lde(j + 10); t3 = lde(j + 11); }
    consume4(c0, c1, c2v, c3);
    c0 = m0; c1 = m1; c2v = m2; c3 = m3;
    m0 = t0; m1 = t1; m2 = t2; m3 = t3;
    j += 4;
  }
  if (full >= 4) consume4(c0, c1, c2v, c3);
  for (int t = full; t < deg; ++t) {
    Edge2 T = lde(t);
    float p = zpart(T);
#pragma unroll
    for (int o = 32; o > 0; o >>= 1) p += __shfl_xor(p, o);
    accum(T, __expf(p));
  }

  float inv = 1.f / ((sacc + 1e-16f) * (float)(deg > 0 ? deg : 1));
  float2 o2;
  o2.x = acc.x * inv + bias[c2];
  o2.y = acc.y * inv + bias[c2 + 1];
  *(float2*)(out + (size_t)n * 128 + c2) = o2;
}

// ---------------- layer-3 (ch=1): one wave per node, edge-parallel lanes ----------------
__global__ void gat3_kernel(const float* __restrict__ xl, const float* __restrict__ xr,
                            const int2* __restrict__ recs, const int* __restrict__ row_ptr,
                            const float* __restrict__ We, const float* __restrict__ att,
                            const float* __restrict__ bias, float* __restrict__ out, int Nn) {
  int n = blockIdx.x * 4 + (threadIdx.x >> 6);
  int lane = threadIdx.x & 63;
  if (n >= Nn) return;
  float we0 = We[0], we1 = We[1], a = att[0];
  float xr_n = xr[n];
  int s0 = row_ptr[n], s1 = row_ptr[n + 1];
  float accp = 0.f, accs = 0.f;
  for (int i = s0 + lane; i < s1; i += 64) {
    int2 r = recs[i];
    f16x2v ea = bc2((unsigned)r.y);
    float xls = xl[r.x];
    float z = xls + xr_n + (float)ea[0] * we0 + (float)ea[1] * we1;
    z = (z > 0.f) ? z : 0.2f * z;
    float p = __expf(z * a);
    accp += p * xls;
    accs += p;
  }
#pragma unroll
  for (int o = 32; o > 0; o >>= 1) {
    accp += __shfl_xor(accp, o);
    accs += __shfl_xor(accs, o);
  }
  int deg = s1 - s0;
  if (lane == 0) out[n] = accp / ((accs + 1e-16f) * (float)(deg > 0 ? deg : 1)) + bias[0];
}

// ---------------- dual row dot: o1[n]=A[n,:].w1, o2[n]=A[n,:].w2 (one A pass) ----------------
__global__ void rowdot2_kernel(const float* __restrict__ A,
                               const float* __restrict__ w1, const float* __restrict__ w2,
                               float* __restrict__ o1, float* __restrict__ o2, int Nn, int K) {
  int n = blockIdx.x * 4 + (threadIdx.x >> 6);
  int lane = threadIdx.x & 63;
  if (n >= Nn) return;
  float p = 0.f, q = 0.f;
  for (int k = lane; k < K; k += 64) {
    float a = A[(size_t)n * K + k];
    p += a * w1[k];
    q += a * w2[k];
  }
#pragma unroll
  for (int o = 32; o > 0; o >>= 1) {
    p += __shfl_xor(p, o);
    q += __shfl_xor(q, o);
  }
  if (lane == 0) { o1[n] = p; o2[n] = q; }
}

extern "C" void kernel_launch(void* const* d_in, const int* in_sizes, int n_in,
                              void* d_out, int out_size, void* d_ws, size_t ws_size,
                              hipStream_t stream) {
  const float* x     = (const float*)d_in[0];
  const int*   ei    = (const int*)d_in[1];
  const float* ea    = (const float*)d_in[2];
  const float* bn0_g = (const float*)d_in[3];
  const float* bn0_b = (const float*)d_in[4];
  const float* Wl1   = (const float*)d_in[5];
  const float* Wr1   = (const float*)d_in[6];
  const float* We1   = (const float*)d_in[7];
  const float* att1  = (const float*)d_in[8];
  const float* b1    = (const float*)d_in[9];
  const float* bn1_g = (const float*)d_in[10];
  const float* bn1_b = (const float*)d_in[11];
  const float* Wl2   = (const float*)d_in[12];
  const float* Wr2   = (const float*)d_in[13];
  const float* We2   = (const float*)d_in[14];
  const float* att2  = (const float*)d_in[15];
  const float* b2    = (const float*)d_in[16];
  const float* bn2_g = (const float*)d_in[17];
  const float* bn2_b = (const float*)d_in[18];
  const float* Wl3   = (const float*)d_in[19];
  const float* Wr3   = (const float*)d_in[20];
  const float* We3   = (const float*)d_in[21];
  const float* att3  = (const float*)d_in[22];
  const float* b3    = (const float*)d_in[23];

  const int F = 301;
  const int Kp1 = 320;
  const int N = in_sizes[0] / F;
  const int E = in_sizes[1] / 2;
  const int* srcv = ei;
  const int* dstv = ei + E;

  // ---- workspace layout, regions time-shared ----
  float* fws = (float*)d_ws;
  float* RA = fws;                              // N*320 f
  float* RB = RA + (size_t)N * 320;             // N*384 f
  float* stats = RB + (size_t)N * 384;          // 1024
  u16* wt1 = (u16*)(stats + 1024);              // 512*320 bf16
  u16* wt2 = wt1 + (size_t)512 * 320;           // 256*256 bf16
  float* xl3 = (float*)(wt2 + (size_t)256 * 256);
  float* xr3 = xl3 + N;
  char* pi = (char*)(xr3 + N);
  pi += (16 - ((size_t)pi & 15)) & 15;          // 16B-align records
  int2* recs = (int2*)pi;                       // E records (8B each)
  int* row_ptr = (int*)(recs + E);              // N+1
  int* fill    = row_ptr + (N + 1);             // N
  int* bsum    = fill + N;                      // nb (<=64)
  int* bexc    = bsum + 64;                     // nb+1

  // region aliases along the timeline
  u16* Abf = (u16*)RA;                          // N x 320 bf16
  u16* xlr1 = (u16*)RB;                         // N x 512 fp16 (xl1 | xr1)
  float* g1out = RA;                            // N x 256 f (gat1 out)
  u16* h1bf = (u16*)RB;                         // N x 256 bf16
  u16* xlr2 = h1bf + (size_t)N * 256;           // N x 256 fp16 (xl2 | xr2)
  float* g2out = RA;                            // N x 128 f
  float* h2 = RA + (size_t)N * 128;             // N x 128 f

  // ---- CSR by dst (parallel 3-phase scan), edge records ----
  int nb = cdiv(N, 1024);
  hipMemsetAsync(fill, 0, (size_t)N * sizeof(int), stream);
  count_kernel<<<cdiv(E, 256), 256, 0, stream>>>(dstv, fill, E);
  scan_blk_kernel<<<nb, 1024, 0, stream>>>(fill, row_ptr, bsum, N);
  scan_kernel<<<1, 1024, 0, stream>>>(bsum, bexc, nb);
  scan_add_kernel<<<cdiv(N, 256), 256, 0, stream>>>(row_ptr, fill, bexc, N, nb);
  scatter_rec_kernel<<<cdiv(E, 256), 256, 0, stream>>>(dstv, srcv, ea, fill, recs, E);

  // ---- weight prep (single bf16 plane) ----
  wt_bf16_kernel<<<cdiv(512 * Kp1, 256), 256, 0, stream>>>(Wl1, Wr1, wt1, F, Kp1, 256);
  wt_bf16_kernel<<<cdiv(256 * 256, 256), 256, 0, stream>>>(Wl2, Wr2, wt2, 256, 256, 128);

  int rows = cdiv(N, GRID_BN);  // high-occupancy BN grids

  // ---- BN0 -> bf16 A plane ----
  hipMemsetAsync(stats, 0, 1024 * sizeof(float), stream);
  col_stats_kernel<<<GRID_BN, 320, 0, stream>>>(x, stats, N, F, rows);
  bn_bf16_kernel<<<GRID_BN, 320, 0, stream>>>(x, Abf, stats, bn0_g, bn0_b, N, F, Kp1, rows, 0);

  // ---- layer 1: fused [xl|xr] bf16 MFMA GEMM (fp16 out) + edge pass ----
  gemm_mfma<u16><<<dim3(cdiv(N, 128), 4), 256, 0, stream>>>(Abf, wt1, xlr1, N, Kp1, 512);
  gat1_kernel<<<cdiv(N, 4), 256, 0, stream>>>(xlr1, xlr1 + 256, 512, recs, row_ptr,
                                              We1, att1, b1, g1out, N);
  // ---- BN1 + relu -> bf16 h1 plane ----
  hipMemsetAsync(stats, 0, 1024 * sizeof(float), stream);
  col_stats_kernel<<<GRID_BN, 256, 0, stream>>>(g1out, stats, N, 256, rows);
  bn_bf16_kernel<<<GRID_BN, 256, 0, stream>>>(g1out, h1bf, stats, bn1_g, bn1_b, N, 256, 256, rows, 1);

  // ---- layer 2: fused [xl|xr] bf16 MFMA GEMM (fp16 out) + edge pass ----
  gemm_mfma<u16><<<dim3(cdiv(N, 128), 2), 256, 0, stream>>>(h1bf, wt2, xlr2, N, 256, 256);
  gat2_kernel<<<cdiv(N, 4), 256, 0, stream>>>(xlr2, xlr2 + 128, 256, recs, row_ptr,
                                              We2, att2, b2, g2out, N);
  // ---- BN2 + relu -> fp32 h2 ----
  hipMemsetAsync(stats, 0, 1024 * sizeof(float), stream);
  col_stats_kernel<<<GRID_BN, 128, 0, stream>>>(g2out, stats, N, 128, rows);
  bn_apply_kernel<<<GRID_BN, 128, 0, stream>>>(g2out, h2, stats, bn2_g, bn2_b, N, 128, 128, rows, 1);

  // ---- layer 3 (ch=1) ----
  rowdot2_kernel<<<cdiv(N, 4), 256, 0, stream>>>(h2, Wl3, Wr3, xl3, xr3, N, 128);
  gat3_kernel<<<cdiv(N, 4), 256, 0, stream>>>(xl3, xr3, recs, row_ptr,
                                              We3, att3, b3, (float*)d_out, N);
}

// Round 18
// 470.374 us; speedup vs baseline: 1.0825x; 1.0656x over previous
//
#include <hip/hip_runtime.h>
#include <hip/hip_fp16.h>

#define EPSF 1e-5f
#define GRID_BN 1024

typedef unsigned short u16;
typedef __attribute__((ext_vector_type(8))) short bf16x8s;  // 8 bf16 (4 VGPRs)
typedef __attribute__((ext_vector_type(4))) float f32x4;
typedef _Float16 f16x2v __attribute__((ext_vector_type(2)));

static inline int cdiv(int a, int b) { return (a + b - 1) / b; }

// round-nearest-even f32 -> bf16 bits
__device__ inline u16 bf_rne(float v) {
  unsigned u = __float_as_uint(v);
  u += 0x7fffu + ((u >> 16) & 1u);
  return (u16)(u >> 16);
}

__device__ inline float4 cvt_h4(uint2 r) {
  float2 a = __half22float2(*(__half2*)&r.x);
  float2 b = __half22float2(*(__half2*)&r.y);
  return make_float4(a.x, a.y, b.x, b.y);
}
__device__ inline float2 cvt_h2(unsigned r) { return __half22float2(*(__half2*)&r); }

// native packed-fp16 helpers (no __h*2 header intrinsics; clang emits v_pk_*)
__device__ inline f16x2v mk2(float x, float y) {
  f16x2v v; v[0] = (_Float16)x; v[1] = (_Float16)y; return v;
}
__device__ inline f16x2v splat2(float x) { return mk2(x, x); }
__device__ inline f16x2v bc2(unsigned r) { return __builtin_bit_cast(f16x2v, r); }

// fp16 pair dot with f32 accumulate (v_dot2_f32_f16); products exact in f32
__device__ inline float fdot2(f16x2v a, f16x2v b, float c) {
#if __has_builtin(__builtin_amdgcn_fdot2)
  return __builtin_amdgcn_fdot2(a, b, c, false);
#else
  return fmaf((float)a[0], (float)b[0], fmaf((float)a[1], (float)b[1], c));
#endif
}

__device__ inline void st_out(float* p, float v) { *p = v; }
__device__ inline void st_out(u16* p, float v) { *p = __half_as_ushort(__float2half(v)); }

// ---------------- column stats (sum, sumsq); X stride == F ----------------
__global__ void col_stats_kernel(const float* __restrict__ X, float* __restrict__ sums,
                                 int N, int F, int rowsPer) {
  int c = threadIdx.x;
  if (c >= F) return;
  int r0 = blockIdx.x * rowsPer;
  int r1 = min(N, r0 + rowsPer);
  float s = 0.f, sq = 0.f;
  for (int r = r0; r < r1; ++r) {
    float v = X[(size_t)r * F + c];
    s += v; sq += v * v;
  }
  atomicAdd(&sums[c], s);
  atomicAdd(&sums[512 + c], sq);
}

// ---------------- BN apply -> single bf16 plane (BN0, BN1) ----------------
__global__ void bn_bf16_kernel(const float* __restrict__ X, u16* __restrict__ Y,
                               const float* __restrict__ sums,
                               const float* __restrict__ g, const float* __restrict__ b,
                               int N, int F, int outW, int rowsPer, int relu) {
  int c = threadIdx.x;
  if (c >= outW) return;
  float sc = 0.f, bb = 0.f;
  if (c < F) {
    float invN = 1.f / (float)N;
    float mu = sums[c] * invN;
    float var = sums[512 + c] * invN - mu * mu;
    sc = g[c] * rsqrtf(var + EPSF);
    bb = b[c] - mu * sc;
  }
  int r0 = blockIdx.x * rowsPer, r1 = min(N, r0 + rowsPer);
  for (int r = r0; r < r1; ++r) {
    float v = (c < F) ? X[(size_t)r * F + c] * sc + bb : 0.f;
    if (relu) v = fmaxf(v, 0.f);
    Y[(size_t)r * outW + c] = bf_rne(v);
  }
}

// ---------------- weights: both layers' transpose+concat+pad+bf16 in ONE launch ----------------
__global__ void wt_both_kernel(const float* __restrict__ Wl1, const float* __restrict__ Wr1,
                               const float* __restrict__ Wl2, const float* __restrict__ Wr2,
                               u16* __restrict__ wt1, u16* __restrict__ wt2) {
  int idx = blockIdx.x * blockDim.x + threadIdx.x;
  const int n1 = 512 * 320;          // layer1: K=301, Kp=320, M=256
  if (idx < n1) {
    int col = idx / 320;
    int k = idx - col * 320;
    float v = 0.f;
    if (k < 301) v = (col < 256) ? Wl1[(size_t)k * 256 + col] : Wr1[(size_t)k * 256 + (col - 256)];
    wt1[idx] = bf_rne(v);
  } else if (idx < n1 + 256 * 256) { // layer2: K=Kp=256, M=128
    int i2 = idx - n1;
    int col = i2 / 256;
    int k = i2 - col * 256;
    float v = (col < 128) ? Wl2[(size_t)k * 128 + col] : Wr2[(size_t)k * 128 + (col - 128)];
    wt2[i2] = bf_rne(v);
  }
}

// ---------------- bf16 MFMA GEMM: C(NxMout) = A B^T ----------------
template <typename OutT>
__global__ __launch_bounds__(256) void gemm_mfma(
    const u16* __restrict__ A, const u16* __restrict__ B,
    OutT* __restrict__ C, int N, int Kp, int ldc) {
  __shared__ u16 sA[128 * 40], sB[128 * 40];
  int tid = threadIdx.x;
  int brow = blockIdx.x * 128, bcol = blockIdx.y * 128;
  int stR = tid >> 1;
  int stC0 = (tid & 1) * 2;
  bool aok = (brow + stR) < N;
  const u16* pA = A + (size_t)(brow + stR) * Kp + stC0 * 8;
  const u16* pB = B + (size_t)(bcol + stR) * Kp + stC0 * 8;
  const uint4 Z = make_uint4(0u, 0u, 0u, 0u);
  uint4 ra0 = aok ? *(const uint4*)(pA) : Z;
  uint4 ra1 = aok ? *(const uint4*)(pA + 8) : Z;
  uint4 rb0 = *(const uint4*)(pB);
  uint4 rb1 = *(const uint4*)(pB + 8);
  f32x4 acc[4][4] = {};
  int lane = tid & 63;
  int wv = tid >> 6, wr = wv >> 1, wc = wv & 1;
  int fr = lane & 15, kch = (lane >> 4) * 8;
  int ldsw = stR * 40 + stC0 * 8;
  for (int k0 = 0;;) {
    __syncthreads();
    *(uint4*)&sA[ldsw] = ra0; *(uint4*)&sA[ldsw + 8] = ra1;
    *(uint4*)&sB[ldsw] = rb0; *(uint4*)&sB[ldsw + 8] = rb1;
    __syncthreads();
    int kn = k0 + 32;
    if (kn < Kp) {  // prefetch next k-slab under the MFMA body
      ra0 = aok ? *(const uint4*)(pA + kn) : Z;
      ra1 = aok ? *(const uint4*)(pA + kn + 8) : Z;
      rb0 = *(const uint4*)(pB + kn);
      rb1 = *(const uint4*)(pB + kn + 8);
    }
    bf16x8s af[4], bf[4];
#pragma unroll
    for (int i = 0; i < 4; ++i) {
      af[i] = *(const bf16x8s*)&sA[(wr * 64 + i * 16 + fr) * 40 + kch];
      bf[i] = *(const bf16x8s*)&sB[(wc * 64 + i * 16 + fr) * 40 + kch];
    }
#pragma unroll
    for (int i = 0; i < 4; ++i)
#pragma unroll
      for (int j = 0; j < 4; ++j)
        acc[i][j] = __builtin_amdgcn_mfma_f32_16x16x32_bf16(af[i], bf[j], acc[i][j], 0, 0, 0);
    k0 = kn;
    if (k0 >= Kp) break;
  }
#pragma unroll
  for (int i = 0; i < 4; ++i) {
    int growb = brow + wr * 64 + i * 16 + (lane >> 4) * 4;
#pragma unroll
    for (int j = 0; j < 4; ++j) {
      int gcol = bcol + wc * 64 + j * 16 + fr;
#pragma unroll
      for (int r = 0; r < 4; ++r) {
        int grow = growb + r;
        if (grow < N) st_out(&C[(size_t)grow * ldc + gcol], acc[i][j][r]);
      }
    }
  }
}

// ---------------- CSR build ----------------
__global__ void count_kernel(const int* __restrict__ dst, int* __restrict__ cnt, int E) {
  int e = blockIdx.x * blockDim.x + threadIdx.x;
  if (e < E) atomicAdd(&cnt[dst[e]], 1);
}

__global__ void scan_blk_kernel(const int* __restrict__ cnt, int* __restrict__ row_ptr,
                                int* __restrict__ bsum, int N) {
  __shared__ int lds[1024];
  int tid = threadIdx.x;
  int i = blockIdx.x * 1024 + tid;
  int v = (i < N) ? cnt[i] : 0;
  lds[tid] = v;
  __syncthreads();
  for (int o = 1; o < 1024; o <<= 1) {
    int t = (tid >= o) ? lds[tid - o] : 0;
    __syncthreads();
    lds[tid] += t;
    __syncthreads();
  }
  if (i < N) row_ptr[i] = lds[tid] - v;
  if (tid == 1023) bsum[blockIdx.x] = lds[1023];
}

__global__ void scan_kernel(const int* __restrict__ cnt, int* __restrict__ row_ptr, int N) {
  __shared__ int lds[1024];
  __shared__ int carry;
  int tid = threadIdx.x;
  if (tid == 0) carry = 0;
  __syncthreads();
  for (int base = 0; base < N; base += 1024) {
    int i = base + tid;
    int v = (i < N) ? cnt[i] : 0;
    lds[tid] = v;
    __syncthreads();
    for (int o = 1; o < 1024; o <<= 1) {
      int t = (tid >= o) ? lds[tid - o] : 0;
      __syncthreads();
      lds[tid] += t;
      __syncthreads();
    }
    int incl = lds[tid];
    if (i < N) row_ptr[i] = carry + incl - v;
    __syncthreads();
    if (tid == 1023) carry += incl;
    __syncthreads();
  }
  if (tid == 0) row_ptr[N] = carry;
}

// adds chunk offsets AND writes the fill[] copy
__global__ void scan_add_kernel(int* __restrict__ row_ptr, int* __restrict__ fill,
                                const int* __restrict__ bexc, int N, int nb) {
  int i = blockIdx.x * blockDim.x + threadIdx.x;
  if (i < N) {
    int v = row_ptr[i] + bexc[i >> 10];
    row_ptr[i] = v;
    fill[i] = v;
  }
  if (i == 0) row_ptr[N] = bexc[nb];
}

// edge records in CSR order: {src, half2(ea0,ea1)} -- 8B
__global__ void scatter_rec_kernel(const int* __restrict__ dst, const int* __restrict__ src,
                                   const float* __restrict__ ea, int* __restrict__ fill,
                                   int2* __restrict__ recs, int E) {
  int e = blockIdx.x * blockDim.x + threadIdx.x;
  if (e < E) {
    int p = atomicAdd(&fill[dst[e]], 1);
    unsigned h0 = __half_as_ushort(__float2half(ea[2 * (size_t)e]));
    unsigned h1 = __half_as_ushort(__float2half(ea[2 * (size_t)e + 1]));
    int2 r;
    r.x = src[e];
    r.y = (int)(h0 | (h1 << 16));
    recs[p] = r;
  }
}

// ---------------- GATv2 layer 1: H=2, D=256 (fp16 xlr), one WAVE per node ----------------
// Triple-buffered 4-edge batches (MLP=8): consume batch j while j+4 arrives and
// j+8 issues. 8B edge records (src + half2 ea) -- no per-edge f32->f16 cvt.
struct Edge1 { uint2 raw; f16x2v ea; };

__global__ __launch_bounds__(256) void gat1_kernel(
    const u16* __restrict__ xl, const u16* __restrict__ xr, int ldx,
    const int2* __restrict__ recs, const int* __restrict__ row_ptr,
    const float* __restrict__ We, const float* __restrict__ att,
    const float* __restrict__ bias, float* __restrict__ out, int Nn) {
  int n = __builtin_amdgcn_readfirstlane(blockIdx.x * 4 + (threadIdx.x >> 6));
  if (n >= Nn) return;
  int lane = threadIdx.x & 63;
  int c4 = lane * 4;
  const float4 we0f = *(const float4*)(We + c4);
  const float4 we1f = *(const float4*)(We + 256 + c4);
  const float4 atf = *(const float4*)(att + c4);
  const f16x2v we0a = mk2(we0f.x, we0f.y), we0b = mk2(we0f.z, we0f.w);
  const f16x2v we1a = mk2(we1f.x, we1f.y), we1b = mk2(we1f.z, we1f.w);
  const f16x2v atta = mk2(atf.x, atf.y), attb = mk2(atf.z, atf.w);
  const f16x2v k02 = splat2(0.2f);
  uint2 xrr = *(const uint2*)(xr + (size_t)n * ldx + c4);
  const f16x2v xra = bc2(xrr.x), xrb = bc2(xrr.y);
  int start = row_ptr[n];
  int deg = row_ptr[n + 1] - start;
  float4 acc = {0.f, 0.f, 0.f, 0.f};
  float sacc = 0.f;

  auto lde = [&](int i) {
    int2 r = recs[start + i];
    Edge1 t;
    int sv = __builtin_amdgcn_readfirstlane(r.x);
    t.ea = bc2((unsigned)r.y);
    t.raw = *(const uint2*)(xl + (size_t)sv * ldx + c4);
    return t;
  };
  auto zpart = [&](const Edge1& t) {
    f16x2v e0h = __builtin_shufflevector(t.ea, t.ea, 0, 0);
    f16x2v e1h = __builtin_shufflevector(t.ea, t.ea, 1, 1);
    f16x2v ra = bc2(t.raw.x), rb = bc2(t.raw.y);
    f16x2v za = e1h * we1a + (e0h * we0a + (ra + xra));
    f16x2v zb = e1h * we1b + (e0h * we0b + (rb + xrb));
    za = __builtin_elementwise_max(za, za * k02);   // leaky for both signs
    zb = __builtin_elementwise_max(zb, zb * k02);
    return fdot2(zb, attb, fdot2(za, atta, 0.f));
  };
  auto accum = [&](const Edge1& t, float p) {
    float4 xc = cvt_h4(t.raw);
    acc.x += p * xc.x;
    acc.y += p * xc.y;
    acc.z += p * xc.z;
    acc.w += p * xc.w;
    sacc += p;
  };
  auto consume4 = [&](const Edge1& A, const Edge1& B, const Edge1& C, const Edge1& D) {
    float p0 = zpart(A), p1 = zpart(B), p2 = zpart(C), p3 = zpart(D);
#pragma unroll
    for (int o = 16; o > 0; o >>= 1) {
      p0 += __shfl_xor(p0, o, 32);
      p1 += __shfl_xor(p1, o, 32);
      p2 += __shfl_xor(p2, o, 32);
      p3 += __shfl_xor(p3, o, 32);
    }
    p0 = __expf(p0); p1 = __expf(p1); p2 = __expf(p2); p3 = __expf(p3);
    accum(A, p0); accum(B, p1); accum(C, p2); accum(D, p3);
  };

  int full = deg & ~3;
  Edge1 c0{}, c1{}, c2{}, c3{}, m0{}, m1{}, m2{}, m3{};
  if (full >= 4) { c0 = lde(0); c1 = lde(1); c2 = lde(2); c3 = lde(3); }
  if (full >= 8) { m0 = lde(4); m1 = lde(5); m2 = lde(6); m3 = lde(7); }
  int j = 0;
  while (j + 8 <= full) {
    Edge1 t0{}, t1{}, t2{}, t3{};
    if (j + 12 <= full) { t0 = lde(j + 8); t1 = lde(j + 9); t2 = lde(j + 10); t3 = lde(j + 11); }
    consume4(c0, c1, c2, c3);
    c0 = m0; c1 = m1; c2 = m2; c3 = m3;
    m0 = t0; m1 = t1; m2 = t2; m3 = t3;
    j += 4;
  }
  if (full >= 4) consume4(c0, c1, c2, c3);
  for (int t = full; t < deg; ++t) {
    Edge1 T = lde(t);
    float p = zpart(T);
#pragma unroll
    for (int o = 16; o > 0; o >>= 1) p += __shfl_xor(p, o, 32);
    accum(T, __expf(p));
  }

  float inv = 1.f / ((sacc + 1e-16f) * (float)(deg > 0 ? deg : 1));
  float4 o4;
  o4.x = acc.x * inv + bias[c4];
  o4.y = acc.y * inv + bias[c4 + 1];
  o4.z = acc.z * inv + bias[c4 + 2];
  o4.w = acc.w * inv + bias[c4 + 3];
  *(float4*)(out + (size_t)n * 256 + c4) = o4;
}

// ---------------- GATv2 layer 2: H=1, D=128 (fp16 xlr), one WAVE per node ----------------
struct Edge2 { unsigned raw; f16x2v ea; };

__global__ __launch_bounds__(256) void gat2_kernel(
    const u16* __restrict__ xl, const u16* __restrict__ xr, int ldx,
    const int2* __restrict__ recs, const int* __restrict__ row_ptr,
    const float* __restrict__ We, const float* __restrict__ att,
    const float* __restrict__ bias, float* __restrict__ out, int Nn) {
  int n = __builtin_amdgcn_readfirstlane(blockIdx.x * 4 + (threadIdx.x >> 6));
  if (n >= Nn) return;
  int lane = threadIdx.x & 63;
  int c2 = lane * 2;
  const float2 we0f = *(const float2*)(We + c2);
  const float2 we1f = *(const float2*)(We + 128 + c2);
  const float2 atf = *(const float2*)(att + c2);
  const f16x2v we0a = mk2(we0f.x, we0f.y);
  const f16x2v we1a = mk2(we1f.x, we1f.y);
  const f16x2v atta = mk2(atf.x, atf.y);
  const f16x2v k02 = splat2(0.2f);
  unsigned xrr = *(const unsigned*)(xr + (size_t)n * ldx + c2);
  const f16x2v xra = bc2(xrr);
  int start = row_ptr[n];
  int deg = row_ptr[n + 1] - start;
  float2 acc = {0.f, 0.f};
  float sacc = 0.f;

  auto lde = [&](int i) {
    int2 r = recs[start + i];
    Edge2 t;
    int sv = __builtin_amdgcn_readfirstlane(r.x);
    t.ea = bc2((unsigned)r.y);
    t.raw = *(const unsigned*)(xl + (size_t)sv * ldx + c2);
    return t;
  };
  auto zpart = [&](const Edge2& t) {
    f16x2v e0h = __builtin_shufflevector(t.ea, t.ea, 0, 0);
    f16x2v e1h = __builtin_shufflevector(t.ea, t.ea, 1, 1);
    f16x2v ra = bc2(t.raw);
    f16x2v za = e1h * we1a + (e0h * we0a + (ra + xra));
    za = __builtin_elementwise_max(za, za * k02);
    return fdot2(za, atta, 0.f);
  };
  auto accum = [&](const Edge2& t, float p) {
    float2 xc = cvt_h2(t.raw);
    acc.x += p * xc.x;
    acc.y += p * xc.y;
    sacc += p;
  };
  auto consume4 = [&](const Edge2& A, const Edge2& B, const Edge2& C, const Edge2& D) {
    float p0 = zpart(A), p1 = zpart(B), p2 = zpart(C), p3 = zpart(D);
#pragma unroll
    for (int o = 32; o > 0; o >>= 1) {
      p0 += __shfl_xor(p0, o);
      p1 += __shfl_xor(p1, o);
      p2 += __shfl_xor(p2, o);
      p3 += __shfl_xor(p3, o);
    }
    p0 = __expf(p0); p1 = __expf(p1); p2 = __expf(p2); p3 = __expf(p3);
    accum(A, p0); accum(B, p1); accum(C, p2); accum(D, p3);
  };

  int full = deg & ~3;
  Edge2 c0{}, c1{}, c2v{}, c3{}, m0{}, m1{}, m2{}, m3{};
  if (full >= 4) { c0 = lde(0); c1 = lde(1); c2v = lde(2); c3 = lde(3); }
  if (full >= 8) { m0 = lde(4); m1 = lde(5); m2 = lde(6); m3 = lde(7); }
  int j = 0;
  while (j + 8 <= full) {
    Edge2 t0{}, t1{}, t2{}, t3{};
    if (j + 12 <= full) { t0 = lde(j + 8); t1 = lde(j + 9); t2 = lde(j + 10); t3 = lde(j + 11); }
    consume4(c0, c1, c2v, c3);
    c0 = m0; c1 = m1; c2v = m2; c3 = m3;
    m0 = t0; m1 = t1; m2 = t2; m3 = t3;
    j += 4;
  }
  if (full >= 4) consume4(c0, c1, c2v, c3);
  for (int t = full; t < deg; ++t) {
    Edge2 T = lde(t);
    float p = zpart(T);
#pragma unroll
    for (int o = 32; o > 0; o >>= 1) p += __shfl_xor(p, o);
    accum(T, __expf(p));
  }

  float inv = 1.f / ((sacc + 1e-16f) * (float)(deg > 0 ? deg : 1));
  float2 o2;
  o2.x = acc.x * inv + bias[c2];
  o2.y = acc.y * inv + bias[c2 + 1];
  *(float2*)(out + (size_t)n * 128 + c2) = o2;
}

// ---------------- layer-3 (ch=1): one wave per node, edge-parallel lanes ----------------
__global__ void gat3_kernel(const float* __restrict__ xl, const float* __restrict__ xr,
                            const int2* __restrict__ recs, const int* __restrict__ row_ptr,
                            const float* __restrict__ We, const float* __restrict__ att,
                            const float* __restrict__ bias, float* __restrict__ out, int Nn) {
  int n = blockIdx.x * 4 + (threadIdx.x >> 6);
  int lane = threadIdx.x & 63;
  if (n >= Nn) return;
  float we0 = We[0], we1 = We[1], a = att[0];
  float xr_n = xr[n];
  int s0 = row_ptr[n], s1 = row_ptr[n + 1];
  float accp = 0.f, accs = 0.f;
  for (int i = s0 + lane; i < s1; i += 64) {
    int2 r = recs[i];
    f16x2v ea = bc2((unsigned)r.y);
    float xls = xl[r.x];
    float z = xls + xr_n + (float)ea[0] * we0 + (float)ea[1] * we1;
    z = (z > 0.f) ? z : 0.2f * z;
    float p = __expf(z * a);
    accp += p * xls;
    accs += p;
  }
#pragma unroll
  for (int o = 32; o > 0; o >>= 1) {
    accp += __shfl_xor(accp, o);
    accs += __shfl_xor(accs, o);
  }
  int deg = s1 - s0;
  if (lane == 0) out[n] = accp / ((accs + 1e-16f) * (float)(deg > 0 ? deg : 1)) + bias[0];
}

// ---------------- fused BN2(scale/bias/relu) + dual row dot over g2out (128 ch) ----------------
// h2 intermediate eliminated: o1[n]=relu(bn(X[n,:])).w1, o2[n]=...w2
__global__ void rowdot2bn_kernel(const float* __restrict__ X, const float* __restrict__ sums,
                                 const float* __restrict__ g, const float* __restrict__ b,
                                 const float* __restrict__ w1, const float* __restrict__ w2,
                                 float* __restrict__ o1, float* __restrict__ o2, int Nn) {
  int n = blockIdx.x * 4 + (threadIdx.x >> 6);
  int lane = threadIdx.x & 63;
  if (n >= Nn) return;
  float p = 0.f, q = 0.f;
  float invN = 1.f / (float)Nn;
#pragma unroll
  for (int kk = 0; kk < 2; ++kk) {
    int c = lane + kk * 64;
    float mu = sums[c] * invN;
    float var = sums[512 + c] * invN - mu * mu;
    float sc = g[c] * rsqrtf(var + EPSF);
    float bb = b[c] - mu * sc;
    float v = fmaxf(X[(size_t)n * 128 + c] * sc + bb, 0.f);
    p += v * w1[c];
    q += v * w2[c];
  }
#pragma unroll
  for (int o = 32; o > 0; o >>= 1) {
    p += __shfl_xor(p, o);
    q += __shfl_xor(q, o);
  }
  if (lane == 0) { o1[n] = p; o2[n] = q; }
}

extern "C" void kernel_launch(void* const* d_in, const int* in_sizes, int n_in,
                              void* d_out, int out_size, void* d_ws, size_t ws_size,
                              hipStream_t stream) {
  const float* x     = (const float*)d_in[0];
  const int*   ei    = (const int*)d_in[1];
  const float* ea    = (const float*)d_in[2];
  const float* bn0_g = (const float*)d_in[3];
  const float* bn0_b = (const float*)d_in[4];
  const float* Wl1   = (const float*)d_in[5];
  const float* Wr1   = (const float*)d_in[6];
  const float* We1   = (const float*)d_in[7];
  const float* att1  = (const float*)d_in[8];
  const float* b1    = (const float*)d_in[9];
  const float* bn1_g = (const float*)d_in[10];
  const float* bn1_b = (const float*)d_in[11];
  const float* Wl2   = (const float*)d_in[12];
  const float* Wr2   = (const float*)d_in[13];
  const float* We2   = (const float*)d_in[14];
  const float* att2  = (const float*)d_in[15];
  const float* b2    = (const float*)d_in[16];
  const float* bn2_g = (const float*)d_in[17];
  const float* bn2_b = (const float*)d_in[18];
  const float* Wl3   = (const float*)d_in[19];
  const float* Wr3   = (const float*)d_in[20];
  const float* We3   = (const float*)d_in[21];
  const float* att3  = (const float*)d_in[22];
  const float* b3    = (const float*)d_in[23];

  const int F = 301;
  const int Kp1 = 320;
  const int N = in_sizes[0] / F;
  const int E = in_sizes[1] / 2;
  const int* srcv = ei;
  const int* dstv = ei + E;

  // ---- workspace layout, regions time-shared ----
  float* fws = (float*)d_ws;
  float* RA = fws;                              // N*320 f
  float* RB = RA + (size_t)N * 320;             // N*384 f
  float* stats = RB + (size_t)N * 384;          // 3*1024 (BN0 | BN1 | BN2)
  float* stats0 = stats;
  float* stats1 = stats + 1024;
  float* stats2 = stats + 2048;
  u16* wt1 = (u16*)(stats + 3072);              // 512*320 bf16
  u16* wt2 = wt1 + (size_t)512 * 320;           // 256*256 bf16
  float* xl3 = (float*)(wt2 + (size_t)256 * 256);
  float* xr3 = xl3 + N;
  char* pi = (char*)(xr3 + N);
  pi += (16 - ((size_t)pi & 15)) & 15;          // 16B-align records
  int2* recs = (int2*)pi;                       // E records (8B each)
  int* row_ptr = (int*)(recs + E);              // N+1
  int* fill    = row_ptr + (N + 1);             // N
  int* bsum    = fill + N;                      // nb (<=64)
  int* bexc    = bsum + 64;                     // nb+1

  // region aliases along the timeline
  u16* Abf = (u16*)RA;                          // N x 320 bf16
  u16* xlr1 = (u16*)RB;                         // N x 512 fp16 (xl1 | xr1)
  float* g1out = RA;                            // N x 256 f (gat1 out)
  u16* h1bf = (u16*)RB;                         // N x 256 bf16
  u16* xlr2 = h1bf + (size_t)N * 256;           // N x 256 fp16 (xl2 | xr2)
  float* g2out = RA;                            // N x 128 f

  // ---- CSR by dst (parallel 3-phase scan), edge records; single stats memset ----
  int nb = cdiv(N, 1024);
  hipMemsetAsync(fill, 0, (size_t)N * sizeof(int), stream);
  hipMemsetAsync(stats, 0, 3072 * sizeof(float), stream);
  count_kernel<<<cdiv(E, 256), 256, 0, stream>>>(dstv, fill, E);
  scan_blk_kernel<<<nb, 1024, 0, stream>>>(fill, row_ptr, bsum, N);
  scan_kernel<<<1, 1024, 0, stream>>>(bsum, bexc, nb);
  scan_add_kernel<<<cdiv(N, 256), 256, 0, stream>>>(row_ptr, fill, bexc, N, nb);
  scatter_rec_kernel<<<cdiv(E, 256), 256, 0, stream>>>(dstv, srcv, ea, fill, recs, E);

  // ---- weight prep (both layers, one launch) ----
  wt_both_kernel<<<cdiv(512 * 320 + 256 * 256, 256), 256, 0, stream>>>(Wl1, Wr1, Wl2, Wr2, wt1, wt2);

  int rows = cdiv(N, GRID_BN);  // high-occupancy BN grids

  // ---- BN0 -> bf16 A plane ----
  col_stats_kernel<<<GRID_BN, 320, 0, stream>>>(x, stats0, N, F, rows);
  bn_bf16_kernel<<<GRID_BN, 320, 0, stream>>>(x, Abf, stats0, bn0_g, bn0_b, N, F, Kp1, rows, 0);

  // ---- layer 1: fused [xl|xr] bf16 MFMA GEMM (fp16 out) + edge pass ----
  gemm_mfma<u16><<<dim3(cdiv(N, 128), 4), 256, 0, stream>>>(Abf, wt1, xlr1, N, Kp1, 512);
  gat1_kernel<<<cdiv(N, 4), 256, 0, stream>>>(xlr1, xlr1 + 256, 512, recs, row_ptr,
                                              We1, att1, b1, g1out, N);
  // ---- BN1 + relu -> bf16 h1 plane ----
  col_stats_kernel<<<GRID_BN, 256, 0, stream>>>(g1out, stats1, N, 256, rows);
  bn_bf16_kernel<<<GRID_BN, 256, 0, stream>>>(g1out, h1bf, stats1, bn1_g, bn1_b, N, 256, 256, rows, 1);

  // ---- layer 2: fused [xl|xr] bf16 MFMA GEMM (fp16 out) + edge pass ----
  gemm_mfma<u16><<<dim3(cdiv(N, 128), 2), 256, 0, stream>>>(h1bf, wt2, xlr2, N, 256, 256);
  gat2_kernel<<<cdiv(N, 4), 256, 0, stream>>>(xlr2, xlr2 + 128, 256, recs, row_ptr,
                                              We2, att2, b2, g2out, N);
  // ---- BN2 stats, then fused BN2-apply + layer-3 row dots (h2 eliminated) ----
  col_stats_kernel<<<GRID_BN, 128, 0, stream>>>(g2out, stats2, N, 128, rows);
  rowdot2bn_kernel<<<cdiv(N, 4), 256, 0, stream>>>(g2out, stats2, bn2_g, bn2_b,
                                                   Wl3, Wr3, xl3, xr3, N);

  // ---- layer 3 (ch=1) ----
  gat3_kernel<<<cdiv(N, 4), 256, 0, stream>>>(xl3, xr3, recs, row_ptr,
                                              We3, att3, b3, (float*)d_out, N);
}